// Round 1
// 2923.860 us; speedup vs baseline: 1.2650x; 1.2650x over previous
//
#include <hip/hip_runtime.h>
#include <hip/hip_fp16.h>
#include <math.h>

#define Bsz 64
#define Tsz 1024
#define Isz 128
#define Hsz 512
#define KH  256   // H/2
#define Osz 10

// ---------------------------------------------------------------------------
// Register-tiled fp32 GEMM: C[M,N] = A[M,K] @ Bw[K,N] + bias[N]
// 64x128 block tile, 8x4 micro-tile, 256 threads.
// ---------------------------------------------------------------------------
__global__ __launch_bounds__(256) void gemm_bias_kernel(
    const float* __restrict__ A, const float* __restrict__ Bw,
    const float* __restrict__ bias, float* __restrict__ C,
    int M, int N, int K)
{
  __shared__ float As[32][68];   // [k][m], padded
  const int tid = threadIdx.x;
  const int m0 = blockIdx.x * 64;
  const int n0 = blockIdx.y * 128;
  const int ty = tid >> 5, tx = tid & 31;

  float acc[8][4] = {{0.f}};

  for (int kk = 0; kk < K; kk += 32) {
    __syncthreads();
#pragma unroll
    for (int i = tid; i < 64 * 32; i += 256) {
      int m = i >> 5, k = i & 31;
      As[k][m] = A[(size_t)(m0 + m) * K + kk + k];
    }
    __syncthreads();
#pragma unroll
    for (int k = 0; k < 32; ++k) {
      const float4 bv = *(const float4*)(&Bw[(size_t)(kk + k) * N + n0 + tx * 4]);
      float a[8];
#pragma unroll
      for (int i = 0; i < 8; ++i) a[i] = As[k][ty * 8 + i];
#pragma unroll
      for (int i = 0; i < 8; ++i) {
        acc[i][0] = fmaf(a[i], bv.x, acc[i][0]);
        acc[i][1] = fmaf(a[i], bv.y, acc[i][1]);
        acc[i][2] = fmaf(a[i], bv.z, acc[i][2]);
        acc[i][3] = fmaf(a[i], bv.w, acc[i][3]);
      }
    }
  }

  const float4 bb = *(const float4*)(&bias[n0 + tx * 4]);
#pragma unroll
  for (int i = 0; i < 8; ++i) {
    float4 v;
    v.x = acc[i][0] + bb.x; v.y = acc[i][1] + bb.y;
    v.z = acc[i][2] + bb.z; v.w = acc[i][3] + bb.w;
    *(float4*)(&C[(size_t)(m0 + ty * 8 + i) * N + n0 + tx * 4]) = v;
  }
}

// ---------------------------------------------------------------------------
// Wc = W_in @ W1a  (128x512 @ 512x256 -> 128x256), one block per row i.
// ---------------------------------------------------------------------------
__global__ __launch_bounds__(256) void wc_kernel(
    const float* __restrict__ W_in, const float* __restrict__ W1a,
    float* __restrict__ Wc)
{
  __shared__ float row[Hsz];
  const int i = blockIdx.x, c = threadIdx.x;
  for (int h = c; h < Hsz; h += 256) row[h] = W_in[(size_t)i * Hsz + h];
  __syncthreads();
  float acc = 0.f;
#pragma unroll 8
  for (int h = 0; h < Hsz; ++h)
    acc = fmaf(row[h], W1a[(size_t)h * KH + c], acc);
  Wc[(size_t)i * KH + c] = acc;
}

// b_U = b_in @ W1a + b_tau1  (256)
__global__ __launch_bounds__(256) void bu_kernel(
    const float* __restrict__ b_in, const float* __restrict__ W1a,
    const float* __restrict__ b_tau1, float* __restrict__ bU)
{
  const int c = threadIdx.x;
  float acc = b_tau1[c];
#pragma unroll 8
  for (int h = 0; h < Hsz; ++h)
    acc = fmaf(b_in[h], W1a[(size_t)h * KH + c], acc);
  bU[c] = acc;
}

// ---------------------------------------------------------------------------
// i8 dot4
// ---------------------------------------------------------------------------
__device__ __forceinline__ int dot4i8(int a, int b, int acc) {
#if __has_builtin(__builtin_amdgcn_sdot4)
  return __builtin_amdgcn_sdot4(a, b, acc, false);
#else
  acc += ((a << 24) >> 24) * ((b << 24) >> 24);
  acc += ((a << 16) >> 24) * ((b << 16) >> 24);
  acc += ((a << 8)  >> 24) * ((b << 8)  >> 24);
  acc += (a >> 24) * (b >> 24);
  return acc;
#endif
}

// ---------------------------------------------------------------------------
// Quantizer layouts: [G groups x C cols] i8; group g, dword di, byte e covers
// source k = 16g + 4di + e; flat dword index = g*(C*4)+c*4+di.
// ---------------------------------------------------------------------------

// drive: col j = output row of W_rec (512 cols, 32 groups over k=512)
__global__ __launch_bounds__(256) void drive_scale_kernel(
    const float* __restrict__ W_rec, float* __restrict__ CS0)
{
  const int j = blockIdx.x * 256 + threadIdx.x;  // 512
  float m = 0.f;
  for (int k = 0; k < Hsz; ++k)
    m = fmaxf(m, fabsf(W_rec[(size_t)j * Hsz + k]));
  CS0[j] = m;
}

__global__ __launch_bounds__(256) void drive_quant_kernel(
    const float* __restrict__ W_rec, const float* __restrict__ CS0,
    unsigned* __restrict__ Q0)
{
  int i = blockIdx.x * 256 + threadIdx.x;  // 65536 dwords
  if (i >= 32 * Hsz * 4) return;
  int di = i & 3, j = (i >> 2) & 511, g = i >> 11;
  int k0 = 16 * g + 4 * di;
  float ma = CS0[j];
  float r = (ma > 0.f) ? (127.f / ma) : 0.f;
  unsigned out = 0;
#pragma unroll
  for (int e = 0; e < 4; ++e) {
    int q = __float2int_rn(W_rec[(size_t)j * Hsz + k0 + e] * r);
    out |= ((unsigned)(q & 255)) << (8 * e);
  }
  Q0[i] = out;
}

// tau1: col c (256 cols), 32 groups over j=512 (source W1b[j][c])
__global__ __launch_bounds__(256) void tau1_scale_kernel(
    const float* __restrict__ W1b, float* __restrict__ CS1)
{
  const int c = threadIdx.x;  // 256
  float m = 0.f;
  for (int j = 0; j < Hsz; ++j)
    m = fmaxf(m, fabsf(W1b[(size_t)j * KH + c]));
  CS1[c] = m;
}

__global__ __launch_bounds__(256) void tau1_quant_kernel(
    const float* __restrict__ W1b, const float* __restrict__ CS1,
    unsigned* __restrict__ Q1)
{
  int i = blockIdx.x * 256 + threadIdx.x;  // 32768 dwords
  if (i >= 32 * KH * 4) return;
  int di = i & 3, c = (i >> 2) & 255, g = i >> 10;
  int j0 = 16 * g + 4 * di;
  float ma = CS1[c];
  float r = (ma > 0.f) ? (127.f / ma) : 0.f;
  unsigned out = 0;
#pragma unroll
  for (int e = 0; e < 4; ++e) {
    int q = __float2int_rn(W1b[(size_t)(j0 + e) * KH + c] * r);
    out |= ((unsigned)(q & 255)) << (8 * e);
  }
  Q1[i] = out;
}

// tau2: col j (512 cols), 16 groups over k=256 (source W_tau2[k][j])
__global__ __launch_bounds__(256) void tau2_scale_kernel(
    const float* __restrict__ W_tau2, float* __restrict__ CS2)
{
  const int j = blockIdx.x * 256 + threadIdx.x;  // 512
  float m = 0.f;
  for (int k = 0; k < KH; ++k)
    m = fmaxf(m, fabsf(W_tau2[(size_t)k * Hsz + j]));
  CS2[j] = m;
}

__global__ __launch_bounds__(256) void tau2_quant_kernel(
    const float* __restrict__ W_tau2, const float* __restrict__ CS2,
    unsigned* __restrict__ Q2)
{
  int i = blockIdx.x * 256 + threadIdx.x;  // 32768 dwords
  if (i >= 16 * Hsz * 4) return;
  int di = i & 3, j = (i >> 2) & 511, g = i >> 11;
  int k0 = 16 * g + 4 * di;
  float ma = CS2[j];
  float r = (ma > 0.f) ? (127.f / ma) : 0.f;
  unsigned out = 0;
#pragma unroll
  for (int e = 0; e < 4; ++e) {
    int q = __float2int_rn(W_tau2[(size_t)(k0 + e) * Hsz + j] * r);
    out |= ((unsigned)(q & 255)) << (8 * e);
  }
  Q2[i] = out;
}

// ---------------------------------------------------------------------------
// Sequential scan. One WG (512 threads) per batch element. All matvecs i8.
//
// R13 change: the scan was at ~90% of the per-CU L2->L1 fill ceiling
// (368 KiB of weight re-fetch per step ~= 5900 cy/step at 64 B/cy/CU; measured
// 7330 cy/step, VALUBusy only ~11%). Weights are step-invariant, so hoist them
// into persistent REGISTERS, loaded once before the t-loop:
//   - Q0 drive groups 0..27  -> w0r[28] = 112 VGPRs/thread
//   - Q1 tau1   groups 0..15 -> w1r[16] =  64 VGPRs/thread
//   - Q0 groups 28,29 stay streamed from L2 (16 KiB/step, hidden under P3
//     compute), groups 30,31 + all of Q2 stay in LDS (144 KiB) as before.
// Per-step global traffic drops 373 KiB -> ~21 KiB; new bound is VALU/LDS.
// xp/U for step t+1 are prefetched at the top of P3 to hide HBM latency.
// ---------------------------------------------------------------------------
__global__ __launch_bounds__(512) void scan_kernel(
    float* __restrict__ xps,           // in: xp [B,T,H]; out: hs [B,T,H]
    const float* __restrict__ U,       // [B,T,KH] (b_tau1 already added)
    const unsigned* __restrict__ Q0,   // i8 drive [32][512][4]
    const unsigned* __restrict__ Q1,   // i8 tau1  [32][256][4]
    const unsigned* __restrict__ Q2,   // i8 tau2  [16][512][4]
    const float* __restrict__ CS0,     // [512]
    const float* __restrict__ CS1,     // [256]
    const float* __restrict__ CS2,     // [512]
    const float* __restrict__ bias,    // [H]
    const float* __restrict__ b_tau2)  // [H]
{
  const int b = blockIdx.x;
  const int tid = threadIdx.x;
  const int hs = tid >> 8;             // tau1 k-half
  const int c  = tid & 255;            // tau1 column

  extern __shared__ __align__(16) uint4 Wlds[];
  __shared__ __align__(16) int Hq[2][128];       // i8 h, double-buffered
  __shared__ __align__(16) unsigned char Aq[KH]; // i8 A (256 B)
  __shared__ float scaleA[4];                    // per-wave A amax
  __shared__ int parti[2][KH];

  const float bias_r = bias[tid];
  const float bt2_r  = b_tau2[tid];
  const float cs0r = CS0[tid] * (1.0f / 16129.0f);  // /127^2
  const float csr  = CS1[c]   * (1.0f / 16129.0f);
  const float cs2r = CS2[tid] * (1.0f / 16129.0f);
  float hold = 0.f;
  if (tid < 128) { Hq[0][tid] = 0; Hq[1][tid] = 0; }

  float* xprow = xps + (size_t)b * Tsz * Hsz;
  const float* Urow = U + (size_t)b * Tsz * KH;

  const uint4* __restrict__ q0 = (const uint4*)Q0 + tid;                 // stride 512
  const uint4* __restrict__ q1 = (const uint4*)Q1 + (size_t)(hs * 16) * 256 + c; // stride 256
  const uint4* __restrict__ q2 = (const uint4*)Q2 + tid;                 // stride 512
  const uint4* Aq4 = (const uint4*)Aq;

  // --- one-time LDS staging: 16 tau2 groups + drive groups 30,31 ---
#pragma unroll
  for (int i = 0; i < 16; ++i)
    Wlds[i * 512 + tid] = q2[(size_t)i * 512];
#pragma unroll
  for (int i = 0; i < 2; ++i)
    Wlds[8192 + i * 512 + tid] = q0[(size_t)(30 + i) * 512];

  // --- one-time REGISTER staging: drive g0..27 (112 VGPR), tau1 all (64) ---
  uint4 w0r[28];
#pragma unroll
  for (int g = 0; g < 28; ++g) w0r[g] = q0[(size_t)g * 512];
  uint4 w1r[16];
#pragma unroll
  for (int g = 0; g < 16; ++g) w1r[g] = q1[(size_t)g * 256];

  __syncthreads();

  // step-0 operands (subsequent steps prefetched inside the loop)
  float xpv = xprow[tid];
  float Uv  = (tid < KH) ? Urow[tid] : 0.f;

  for (int t = 0; t < Tsz; ++t) {
    const uint4* h4 = (const uint4*)Hq[t & 1];

    // --- P1: tau1 partial (i8), 16 groups from registers ---
    int a0 = 0, a1 = 0;
#pragma unroll
    for (int g = 0; g < 16; ++g) {
      const uint4 w  = w1r[g];
      const uint4 hv = h4[hs * 16 + g];
      a0 = dot4i8((int)w.x, (int)hv.x, a0); a1 = dot4i8((int)w.y, (int)hv.y, a1);
      a0 = dot4i8((int)w.z, (int)hv.z, a0); a1 = dot4i8((int)w.w, (int)hv.w, a1);
    }
    parti[hs][c] = a0 + a1;
    __syncthreads();                                   // sync1

    // --- P2: A + per-wave (64-lane segment) quantization ---
    if (tid < KH) {
      float aval = fmaxf(Uv + (float)(parti[0][tid] + parti[1][tid]) * csr, 0.f);
      float m = aval;
#pragma unroll
      for (int off = 32; off >= 1; off >>= 1)
        m = fmaxf(m, __shfl_xor(m, off));
      if ((tid & 63) == 0) scaleA[tid >> 6] = m;
      const float r = (m > 0.f) ? (127.f / m) : 0.f;
      Aq[tid] = (unsigned char)__float2int_rn(aval * r);
    }
    __syncthreads();                                   // sync2

    // prefetch next-step xp/U (one row ahead; last step reads into the next
    // workspace region -- mapped memory, value discarded)
    const float xpn = xprow[Hsz + tid];
    const float Un  = (tid < KH) ? Urow[KH + tid] : 0.f;

    // --- P3: drive (28 reg groups + 2 streamed + 2 LDS) fused with tau2 ---
    int d0i = 0, d1i = 0;
    int t2a0 = 0, t2a1 = 0;
    float s = bt2_r;
#pragma unroll
    for (int g = 0; g < 16; ++g) {
      uint4 w0, w1;
      if (g < 14) {
        w0 = w0r[2 * g];
        w1 = w0r[2 * g + 1];
      } else if (g == 14) {
        w0 = q0[(size_t)28 * 512];
        w1 = q0[(size_t)29 * 512];
      } else {
        w0 = Wlds[8192 + tid];
        w1 = Wlds[8192 + 512 + tid];
      }
      const uint4 hv0 = h4[2 * g], hv1 = h4[2 * g + 1];
      d0i = dot4i8((int)w0.x, (int)hv0.x, d0i); d1i = dot4i8((int)w0.y, (int)hv0.y, d1i);
      d0i = dot4i8((int)w0.z, (int)hv0.z, d0i); d1i = dot4i8((int)w0.w, (int)hv0.w, d1i);
      d0i = dot4i8((int)w1.x, (int)hv1.x, d0i); d1i = dot4i8((int)w1.y, (int)hv1.y, d1i);
      d0i = dot4i8((int)w1.z, (int)hv1.z, d0i); d1i = dot4i8((int)w1.w, (int)hv1.w, d1i);

      const uint4 wt = Wlds[g * 512 + tid];
      const uint4 av = Aq4[g];
      t2a0 = dot4i8((int)wt.x, (int)av.x, t2a0); t2a1 = dot4i8((int)wt.y, (int)av.y, t2a1);
      t2a0 = dot4i8((int)wt.z, (int)av.z, t2a0); t2a1 = dot4i8((int)wt.w, (int)av.w, t2a1);
      if ((g & 3) == 3) {
        s += (float)(t2a0 + t2a1) * cs2r * scaleA[g >> 2];
        t2a0 = 0; t2a1 = 0;
      }
    }

    // --- epilogue: tau, tanh, Euler update ---
    const float d = xpv + bias_r + (float)(d0i + d1i) * cs0r;
    const float tau = 5.0f + 45.0f / (1.0f + __expf(-s));
    const float e2 = __expf(2.0f * d);
    const float drv = 1.0f - 2.0f / (e2 + 1.0f);       // tanh
    const float hnew = hold + (drv - hold) / tau;
    hold = hnew;
    ((char*)Hq[(t + 1) & 1])[tid] = (char)(__float2int_rn(hnew * 127.f) & 255);
    xprow[tid] = hnew;                                 // hs output (dead xp slot)
    __syncthreads();                                   // sync3

    xpv = xpn; Uv = Un;
    xprow += Hsz;
    Urow  += KH;
  }
}

// ---------------------------------------------------------------------------
// Epilogue: out[m,o] = hs[m,:] @ W_out[:,o] + b_out[o].
// 16 rows/block staged to LDS via coalesced float4 (+4 pad to spread banks);
// W_out also in LDS. Inner loop = b128 LDS h-reads + scalar LDS W + FMA.
// ---------------------------------------------------------------------------
__global__ __launch_bounds__(256) void outproj_kernel(
    const float* __restrict__ hs, const float* __restrict__ W_out,
    const float* __restrict__ b_out, float* __restrict__ out)
{
  __shared__ float hsL[16][516];       // 516 = 512+4: rows spread across banks
  __shared__ float WL[Hsz * Osz];      // 20 KB
  const int tid = threadIdx.x;
  const size_t m0 = (size_t)blockIdx.x * 16;

  for (int i = tid; i < Hsz * Osz; i += 256) WL[i] = W_out[i];

  const float4* src = (const float4*)(hs + m0 * Hsz);  // 2048 float4, contiguous
#pragma unroll
  for (int i = 0; i < 8; ++i) {
    int idx = i * 256 + tid;
    *(float4*)&hsL[idx >> 7][(idx & 127) * 4] = src[idx];
  }
  __syncthreads();

  const int r = tid >> 4, o = tid & 15;
  if (o < Osz) {
    float acc = b_out[o];
#pragma unroll 8
    for (int k4 = 0; k4 < 128; ++k4) {
      const float4 h4 = *(const float4*)&hsL[r][k4 * 4];
      acc = fmaf(h4.x, WL[(4 * k4 + 0) * Osz + o], acc);
      acc = fmaf(h4.y, WL[(4 * k4 + 1) * Osz + o], acc);
      acc = fmaf(h4.z, WL[(4 * k4 + 2) * Osz + o], acc);
      acc = fmaf(h4.w, WL[(4 * k4 + 3) * Osz + o], acc);
    }
    out[(m0 + r) * Osz + o] = acc;
  }
}

// ---------------------------------------------------------------------------
extern "C" void kernel_launch(void* const* d_in, const int* in_sizes, int n_in,
                              void* d_out, int out_size, void* d_ws, size_t ws_size,
                              hipStream_t stream) {
  (void)in_sizes; (void)n_in; (void)out_size; (void)ws_size;

  const float* x      = (const float*)d_in[0];
  const float* W_in   = (const float*)d_in[1];
  const float* b_in   = (const float*)d_in[2];
  const float* W_rec  = (const float*)d_in[3];
  const float* bias   = (const float*)d_in[4];
  const float* W_tau1 = (const float*)d_in[5];
  const float* b_tau1 = (const float*)d_in[6];
  const float* W_tau2 = (const float*)d_in[7];
  const float* b_tau2 = (const float*)d_in[8];
  const float* W_out  = (const float*)d_in[9];
  const float* b_out  = (const float*)d_in[10];
  float* out = (float*)d_out;

  char* ws = (char*)d_ws;
  size_t off = 0;
  float* xps = (float*)(ws + off); off += (size_t)Bsz * Tsz * Hsz * 4;  // 128 MiB
  float* U   = (float*)(ws + off); off += (size_t)Bsz * Tsz * KH * 4;   //  64 MiB
  unsigned* Q0 = (unsigned*)(ws + off); off += (size_t)32 * Hsz * 4 * 4;// 256 KiB
  unsigned* Q1 = (unsigned*)(ws + off); off += (size_t)32 * KH  * 4 * 4;// 128 KiB
  unsigned* Q2 = (unsigned*)(ws + off); off += (size_t)16 * Hsz * 4 * 4;// 128 KiB
  float* CS0   = (float*)(ws + off); off += 512 * 4;
  float* CS1   = (float*)(ws + off); off += 256 * 4;
  float* CS2   = (float*)(ws + off); off += 512 * 4;
  float* Wc    = (float*)(ws + off); off += (size_t)Isz * KH * 4;       // 128 KiB
  float* bU    = (float*)(ws + off); off += 256 * 4;

  const float* W1a = W_tau1;                     // rows 0..511
  const float* W1b = W_tau1 + (size_t)Hsz * KH;  // rows 512..1023

  const int M = Bsz * Tsz;  // 65536

  // opt-in to 144 KB dynamic LDS for the scan kernel
  (void)hipFuncSetAttribute((const void*)scan_kernel,
                            hipFuncAttributeMaxDynamicSharedMemorySize, 147456);

  // weight quantization + fused-U weight precompute (all small, independent)
  drive_scale_kernel<<<2, 256, 0, stream>>>(W_rec, CS0);
  drive_quant_kernel<<<256, 256, 0, stream>>>(W_rec, CS0, Q0);
  tau1_scale_kernel<<<1, 256, 0, stream>>>(W1b, CS1);
  tau1_quant_kernel<<<128, 256, 0, stream>>>(W1b, CS1, Q1);
  tau2_scale_kernel<<<2, 256, 0, stream>>>(W_tau2, CS2);
  tau2_quant_kernel<<<128, 256, 0, stream>>>(W_tau2, CS2, Q2);
  wc_kernel<<<Isz, 256, 0, stream>>>(W_in, W1a, Wc);
  bu_kernel<<<1, 256, 0, stream>>>(b_in, W1a, b_tau1, bU);

  // xp = x @ W_in + b_in            [65536,128]@[128,512]
  {
    dim3 grid(M / 64, Hsz / 128);
    gemm_bias_kernel<<<grid, 256, 0, stream>>>(x, W_in, b_in, xps, M, Hsz, Isz);
  }
  // U = x @ Wc + bU                 [65536,128]@[128,256]  (== xp@W1a + b_tau1)
  {
    dim3 grid(M / 64, KH / 128);
    gemm_bias_kernel<<<grid, 256, 0, stream>>>(x, Wc, bU, U, M, KH, Isz);
  }
  // scan (64 WGs, one per batch element; 144 KB dynamic LDS)
  scan_kernel<<<Bsz, 512, 147456, stream>>>(xps, U, Q0, Q1, Q2,
                                            CS0, CS1, CS2, bias, b_tau2);
  // output projection
  outproj_kernel<<<M / 16, 256, 0, stream>>>(xps, W_out, b_out, out);
}

// Round 2
// 2897.048 us; speedup vs baseline: 1.2767x; 1.0093x over previous
//
#include <hip/hip_runtime.h>
#include <hip/hip_fp16.h>
#include <math.h>

#define Bsz 64
#define Tsz 1024
#define Isz 128
#define Hsz 512
#define KH  256   // H/2
#define Osz 10

// ---------------------------------------------------------------------------
// Register-tiled fp32 GEMM: C[M,N] = A[M,K] @ Bw[K,N] + bias[N]
// 64x128 block tile, 8x4 micro-tile, 256 threads.
// ---------------------------------------------------------------------------
__global__ __launch_bounds__(256) void gemm_bias_kernel(
    const float* __restrict__ A, const float* __restrict__ Bw,
    const float* __restrict__ bias, float* __restrict__ C,
    int M, int N, int K)
{
  __shared__ float As[32][68];   // [k][m], padded
  const int tid = threadIdx.x;
  const int m0 = blockIdx.x * 64;
  const int n0 = blockIdx.y * 128;
  const int ty = tid >> 5, tx = tid & 31;

  float acc[8][4] = {{0.f}};

  for (int kk = 0; kk < K; kk += 32) {
    __syncthreads();
#pragma unroll
    for (int i = tid; i < 64 * 32; i += 256) {
      int m = i >> 5, k = i & 31;
      As[k][m] = A[(size_t)(m0 + m) * K + kk + k];
    }
    __syncthreads();
#pragma unroll
    for (int k = 0; k < 32; ++k) {
      const float4 bv = *(const float4*)(&Bw[(size_t)(kk + k) * N + n0 + tx * 4]);
      float a[8];
#pragma unroll
      for (int i = 0; i < 8; ++i) a[i] = As[k][ty * 8 + i];
#pragma unroll
      for (int i = 0; i < 8; ++i) {
        acc[i][0] = fmaf(a[i], bv.x, acc[i][0]);
        acc[i][1] = fmaf(a[i], bv.y, acc[i][1]);
        acc[i][2] = fmaf(a[i], bv.z, acc[i][2]);
        acc[i][3] = fmaf(a[i], bv.w, acc[i][3]);
      }
    }
  }

  const float4 bb = *(const float4*)(&bias[n0 + tx * 4]);
#pragma unroll
  for (int i = 0; i < 8; ++i) {
    float4 v;
    v.x = acc[i][0] + bb.x; v.y = acc[i][1] + bb.y;
    v.z = acc[i][2] + bb.z; v.w = acc[i][3] + bb.w;
    *(float4*)(&C[(size_t)(m0 + ty * 8 + i) * N + n0 + tx * 4]) = v;
  }
}

// ---------------------------------------------------------------------------
// Wc = W_in @ W1a  (128x512 @ 512x256 -> 128x256), one block per row i.
// ---------------------------------------------------------------------------
__global__ __launch_bounds__(256) void wc_kernel(
    const float* __restrict__ W_in, const float* __restrict__ W1a,
    float* __restrict__ Wc)
{
  __shared__ float row[Hsz];
  const int i = blockIdx.x, c = threadIdx.x;
  for (int h = c; h < Hsz; h += 256) row[h] = W_in[(size_t)i * Hsz + h];
  __syncthreads();
  float acc = 0.f;
#pragma unroll 8
  for (int h = 0; h < Hsz; ++h)
    acc = fmaf(row[h], W1a[(size_t)h * KH + c], acc);
  Wc[(size_t)i * KH + c] = acc;
}

// b_U = b_in @ W1a + b_tau1  (256)
__global__ __launch_bounds__(256) void bu_kernel(
    const float* __restrict__ b_in, const float* __restrict__ W1a,
    const float* __restrict__ b_tau1, float* __restrict__ bU)
{
  const int c = threadIdx.x;
  float acc = b_tau1[c];
#pragma unroll 8
  for (int h = 0; h < Hsz; ++h)
    acc = fmaf(b_in[h], W1a[(size_t)h * KH + c], acc);
  bU[c] = acc;
}

// ---------------------------------------------------------------------------
// i8 dot4
// ---------------------------------------------------------------------------
__device__ __forceinline__ int dot4i8(int a, int b, int acc) {
#if __has_builtin(__builtin_amdgcn_sdot4)
  return __builtin_amdgcn_sdot4(a, b, acc, false);
#else
  acc += ((a << 24) >> 24) * ((b << 24) >> 24);
  acc += ((a << 16) >> 24) * ((b << 16) >> 24);
  acc += ((a << 8)  >> 24) * ((b << 8)  >> 24);
  acc += (a >> 24) * (b >> 24);
  return acc;
#endif
}

// ---------------------------------------------------------------------------
// Quantizer layouts: [G groups x C cols] i8; group g, dword di, byte e covers
// source k = 16g + 4di + e; flat dword index = g*(C*4)+c*4+di.
// ---------------------------------------------------------------------------

// drive: col j = output row of W_rec (512 cols, 32 groups over k=512)
__global__ __launch_bounds__(256) void drive_scale_kernel(
    const float* __restrict__ W_rec, float* __restrict__ CS0)
{
  const int j = blockIdx.x * 256 + threadIdx.x;  // 512
  float m = 0.f;
  for (int k = 0; k < Hsz; ++k)
    m = fmaxf(m, fabsf(W_rec[(size_t)j * Hsz + k]));
  CS0[j] = m;
}

__global__ __launch_bounds__(256) void drive_quant_kernel(
    const float* __restrict__ W_rec, const float* __restrict__ CS0,
    unsigned* __restrict__ Q0)
{
  int i = blockIdx.x * 256 + threadIdx.x;  // 65536 dwords
  if (i >= 32 * Hsz * 4) return;
  int di = i & 3, j = (i >> 2) & 511, g = i >> 11;
  int k0 = 16 * g + 4 * di;
  float ma = CS0[j];
  float r = (ma > 0.f) ? (127.f / ma) : 0.f;
  unsigned out = 0;
#pragma unroll
  for (int e = 0; e < 4; ++e) {
    int q = __float2int_rn(W_rec[(size_t)j * Hsz + k0 + e] * r);
    out |= ((unsigned)(q & 255)) << (8 * e);
  }
  Q0[i] = out;
}

// tau1: col c (256 cols), 32 groups over j=512 (source W1b[j][c])
__global__ __launch_bounds__(256) void tau1_scale_kernel(
    const float* __restrict__ W1b, float* __restrict__ CS1)
{
  const int c = threadIdx.x;  // 256
  float m = 0.f;
  for (int j = 0; j < Hsz; ++j)
    m = fmaxf(m, fabsf(W1b[(size_t)j * KH + c]));
  CS1[c] = m;
}

__global__ __launch_bounds__(256) void tau1_quant_kernel(
    const float* __restrict__ W1b, const float* __restrict__ CS1,
    unsigned* __restrict__ Q1)
{
  int i = blockIdx.x * 256 + threadIdx.x;  // 32768 dwords
  if (i >= 32 * KH * 4) return;
  int di = i & 3, c = (i >> 2) & 255, g = i >> 10;
  int j0 = 16 * g + 4 * di;
  float ma = CS1[c];
  float r = (ma > 0.f) ? (127.f / ma) : 0.f;
  unsigned out = 0;
#pragma unroll
  for (int e = 0; e < 4; ++e) {
    int q = __float2int_rn(W1b[(size_t)(j0 + e) * KH + c] * r);
    out |= ((unsigned)(q & 255)) << (8 * e);
  }
  Q1[i] = out;
}

// tau2: col j (512 cols), 16 groups over k=256 (source W_tau2[k][j])
__global__ __launch_bounds__(256) void tau2_scale_kernel(
    const float* __restrict__ W_tau2, float* __restrict__ CS2)
{
  const int j = blockIdx.x * 256 + threadIdx.x;  // 512
  float m = 0.f;
  for (int k = 0; k < KH; ++k)
    m = fmaxf(m, fabsf(W_tau2[(size_t)k * Hsz + j]));
  CS2[j] = m;
}

__global__ __launch_bounds__(256) void tau2_quant_kernel(
    const float* __restrict__ W_tau2, const float* __restrict__ CS2,
    unsigned* __restrict__ Q2)
{
  int i = blockIdx.x * 256 + threadIdx.x;  // 32768 dwords
  if (i >= 16 * Hsz * 4) return;
  int di = i & 3, j = (i >> 2) & 511, g = i >> 11;
  int k0 = 16 * g + 4 * di;
  float ma = CS2[j];
  float r = (ma > 0.f) ? (127.f / ma) : 0.f;
  unsigned out = 0;
#pragma unroll
  for (int e = 0; e < 4; ++e) {
    int q = __float2int_rn(W_tau2[(size_t)(k0 + e) * Hsz + j] * r);
    out |= ((unsigned)(q & 255)) << (8 * e);
  }
  Q2[i] = out;
}

// ---------------------------------------------------------------------------
// Sequential scan. One WG (512 threads) per batch element. All matvecs i8.
//
// R14 change: R13 hoisted 176 uint4-words of weights to registers, but
// __launch_bounds__(512) let the allocator cap at 128 VGPRs (4 waves/SIMD
// target) and it sank the loads back into the loop. Occupancy is 1 WG/CU
// anyway (144 KB LDS), i.e. 2 waves/SIMD, so 256 VGPRs are free:
//   __launch_bounds__(512, 2)  -> unlock the 256-VGPR tier.
// Persistent registers trimmed for headroom: drive g0..25 (104 VGPR) +
// tau1 g0..15 (64 VGPR) = 168. Drive g26..29 streamed from L2 each step
// (32 KiB/step, loads issued at loop top -> latency hidden under P1/P2);
// g30,31 + all tau2 in LDS (144 KB) as before.
// ---------------------------------------------------------------------------
__global__ __launch_bounds__(512, 2) void scan_kernel(
    float* __restrict__ xps,           // in: xp [B,T,H]; out: hs [B,T,H]
    const float* __restrict__ U,       // [B,T,KH] (b_tau1 already added)
    const unsigned* __restrict__ Q0,   // i8 drive [32][512][4]
    const unsigned* __restrict__ Q1,   // i8 tau1  [32][256][4]
    const unsigned* __restrict__ Q2,   // i8 tau2  [16][512][4]
    const float* __restrict__ CS0,     // [512]
    const float* __restrict__ CS1,     // [256]
    const float* __restrict__ CS2,     // [512]
    const float* __restrict__ bias,    // [H]
    const float* __restrict__ b_tau2)  // [H]
{
  const int b = blockIdx.x;
  const int tid = threadIdx.x;
  const int hs = tid >> 8;             // tau1 k-half
  const int c  = tid & 255;            // tau1 column

  extern __shared__ __align__(16) uint4 Wlds[];
  __shared__ __align__(16) int Hq[2][128];       // i8 h, double-buffered
  __shared__ __align__(16) unsigned char Aq[KH]; // i8 A (256 B)
  __shared__ float scaleA[4];                    // per-wave A amax
  __shared__ int parti[2][KH];

  const float bias_r = bias[tid];
  const float bt2_r  = b_tau2[tid];
  const float cs0r = CS0[tid] * (1.0f / 16129.0f);  // /127^2
  const float csr  = CS1[c]   * (1.0f / 16129.0f);
  const float cs2r = CS2[tid] * (1.0f / 16129.0f);
  float hold = 0.f;
  if (tid < 128) { Hq[0][tid] = 0; Hq[1][tid] = 0; }

  float* xprow = xps + (size_t)b * Tsz * Hsz;
  const float* Urow = U + (size_t)b * Tsz * KH;

  const uint4* __restrict__ q0 = (const uint4*)Q0 + tid;                 // stride 512
  const uint4* __restrict__ q1 = (const uint4*)Q1 + (size_t)(hs * 16) * 256 + c; // stride 256
  const uint4* __restrict__ q2 = (const uint4*)Q2 + tid;                 // stride 512
  const uint4* Aq4 = (const uint4*)Aq;

  // --- one-time LDS staging: 16 tau2 groups + drive groups 30,31 ---
#pragma unroll
  for (int i = 0; i < 16; ++i)
    Wlds[i * 512 + tid] = q2[(size_t)i * 512];
#pragma unroll
  for (int i = 0; i < 2; ++i)
    Wlds[8192 + i * 512 + tid] = q0[(size_t)(30 + i) * 512];

  // --- one-time REGISTER staging: drive g0..25 (104 VGPR), tau1 all (64) ---
  uint4 w0r[26];
#pragma unroll
  for (int g = 0; g < 26; ++g) w0r[g] = q0[(size_t)g * 512];
  uint4 w1r[16];
#pragma unroll
  for (int g = 0; g < 16; ++g) w1r[g] = q1[(size_t)g * 256];

  __syncthreads();

  // step-0 operands (subsequent steps prefetched inside the loop)
  float xpv = xprow[tid];
  float Uv  = (tid < KH) ? Urow[tid] : 0.f;

  for (int t = 0; t < Tsz; ++t) {
    const uint4* h4 = (const uint4*)Hq[t & 1];

    // streamed drive groups 26..29 -- issued first so L2 latency hides
    // under P1/P2 (values are step-invariant; if the allocator has room
    // it may hoist these, which is equally fine)
    const uint4 s26 = q0[(size_t)26 * 512];
    const uint4 s27 = q0[(size_t)27 * 512];
    const uint4 s28 = q0[(size_t)28 * 512];
    const uint4 s29 = q0[(size_t)29 * 512];

    // --- P1: tau1 partial (i8), 16 groups from registers ---
    int a0 = 0, a1 = 0;
#pragma unroll
    for (int g = 0; g < 16; ++g) {
      const uint4 w  = w1r[g];
      const uint4 hv = h4[hs * 16 + g];
      a0 = dot4i8((int)w.x, (int)hv.x, a0); a1 = dot4i8((int)w.y, (int)hv.y, a1);
      a0 = dot4i8((int)w.z, (int)hv.z, a0); a1 = dot4i8((int)w.w, (int)hv.w, a1);
    }
    parti[hs][c] = a0 + a1;
    __syncthreads();                                   // sync1

    // --- P2: A + per-wave (64-lane segment) quantization ---
    if (tid < KH) {
      float aval = fmaxf(Uv + (float)(parti[0][tid] + parti[1][tid]) * csr, 0.f);
      float m = aval;
#pragma unroll
      for (int off = 32; off >= 1; off >>= 1)
        m = fmaxf(m, __shfl_xor(m, off));
      if ((tid & 63) == 0) scaleA[tid >> 6] = m;
      const float r = (m > 0.f) ? (127.f / m) : 0.f;
      Aq[tid] = (unsigned char)__float2int_rn(aval * r);
    }
    __syncthreads();                                   // sync2

    // prefetch next-step xp/U (one row ahead; last step reads into the next
    // workspace region -- mapped memory, value discarded)
    const float xpn = xprow[Hsz + tid];
    const float Un  = (tid < KH) ? Urow[KH + tid] : 0.f;

    // --- P3: drive (26 reg + 4 streamed + 2 LDS groups) fused with tau2 ---
    int d0i = 0, d1i = 0;
    int t2a0 = 0, t2a1 = 0;
    float s = bt2_r;
#pragma unroll
    for (int g = 0; g < 16; ++g) {
      uint4 w0, w1;
      if (g < 13) {
        w0 = w0r[2 * g];
        w1 = w0r[2 * g + 1];
      } else if (g == 13) {
        w0 = s26; w1 = s27;
      } else if (g == 14) {
        w0 = s28; w1 = s29;
      } else {
        w0 = Wlds[8192 + tid];
        w1 = Wlds[8192 + 512 + tid];
      }
      const uint4 hv0 = h4[2 * g], hv1 = h4[2 * g + 1];
      d0i = dot4i8((int)w0.x, (int)hv0.x, d0i); d1i = dot4i8((int)w0.y, (int)hv0.y, d1i);
      d0i = dot4i8((int)w0.z, (int)hv0.z, d0i); d1i = dot4i8((int)w0.w, (int)hv0.w, d1i);
      d0i = dot4i8((int)w1.x, (int)hv1.x, d0i); d1i = dot4i8((int)w1.y, (int)hv1.y, d1i);
      d0i = dot4i8((int)w1.z, (int)hv1.z, d0i); d1i = dot4i8((int)w1.w, (int)hv1.w, d1i);

      const uint4 wt = Wlds[g * 512 + tid];
      const uint4 av = Aq4[g];
      t2a0 = dot4i8((int)wt.x, (int)av.x, t2a0); t2a1 = dot4i8((int)wt.y, (int)av.y, t2a1);
      t2a0 = dot4i8((int)wt.z, (int)av.z, t2a0); t2a1 = dot4i8((int)wt.w, (int)av.w, t2a1);
      if ((g & 3) == 3) {
        s += (float)(t2a0 + t2a1) * cs2r * scaleA[g >> 2];
        t2a0 = 0; t2a1 = 0;
      }
    }

    // --- epilogue: tau, tanh, Euler update ---
    const float d = xpv + bias_r + (float)(d0i + d1i) * cs0r;
    const float tau = 5.0f + 45.0f / (1.0f + __expf(-s));
    const float e2 = __expf(2.0f * d);
    const float drv = 1.0f - 2.0f / (e2 + 1.0f);       // tanh
    const float hnew = hold + (drv - hold) / tau;
    hold = hnew;
    ((char*)Hq[(t + 1) & 1])[tid] = (char)(__float2int_rn(hnew * 127.f) & 255);
    xprow[tid] = hnew;                                 // hs output (dead xp slot)
    __syncthreads();                                   // sync3

    xpv = xpn; Uv = Un;
    xprow += Hsz;
    Urow  += KH;
  }
}

// ---------------------------------------------------------------------------
// Epilogue: out[m,o] = hs[m,:] @ W_out[:,o] + b_out[o].
// 16 rows/block staged to LDS via coalesced float4 (+4 pad to spread banks);
// W_out also in LDS. Inner loop = b128 LDS h-reads + scalar LDS W + FMA.
// ---------------------------------------------------------------------------
__global__ __launch_bounds__(256) void outproj_kernel(
    const float* __restrict__ hs, const float* __restrict__ W_out,
    const float* __restrict__ b_out, float* __restrict__ out)
{
  __shared__ float hsL[16][516];       // 516 = 512+4: rows spread across banks
  __shared__ float WL[Hsz * Osz];      // 20 KB
  const int tid = threadIdx.x;
  const size_t m0 = (size_t)blockIdx.x * 16;

  for (int i = tid; i < Hsz * Osz; i += 256) WL[i] = W_out[i];

  const float4* src = (const float4*)(hs + m0 * Hsz);  // 2048 float4, contiguous
#pragma unroll
  for (int i = 0; i < 8; ++i) {
    int idx = i * 256 + tid;
    *(float4*)&hsL[idx >> 7][(idx & 127) * 4] = src[idx];
  }
  __syncthreads();

  const int r = tid >> 4, o = tid & 15;
  if (o < Osz) {
    float acc = b_out[o];
#pragma unroll 8
    for (int k4 = 0; k4 < 128; ++k4) {
      const float4 h4 = *(const float4*)&hsL[r][k4 * 4];
      acc = fmaf(h4.x, WL[(4 * k4 + 0) * Osz + o], acc);
      acc = fmaf(h4.y, WL[(4 * k4 + 1) * Osz + o], acc);
      acc = fmaf(h4.z, WL[(4 * k4 + 2) * Osz + o], acc);
      acc = fmaf(h4.w, WL[(4 * k4 + 3) * Osz + o], acc);
    }
    out[(m0 + r) * Osz + o] = acc;
  }
}

// ---------------------------------------------------------------------------
extern "C" void kernel_launch(void* const* d_in, const int* in_sizes, int n_in,
                              void* d_out, int out_size, void* d_ws, size_t ws_size,
                              hipStream_t stream) {
  (void)in_sizes; (void)n_in; (void)out_size; (void)ws_size;

  const float* x      = (const float*)d_in[0];
  const float* W_in   = (const float*)d_in[1];
  const float* b_in   = (const float*)d_in[2];
  const float* W_rec  = (const float*)d_in[3];
  const float* bias   = (const float*)d_in[4];
  const float* W_tau1 = (const float*)d_in[5];
  const float* b_tau1 = (const float*)d_in[6];
  const float* W_tau2 = (const float*)d_in[7];
  const float* b_tau2 = (const float*)d_in[8];
  const float* W_out  = (const float*)d_in[9];
  const float* b_out  = (const float*)d_in[10];
  float* out = (float*)d_out;

  char* ws = (char*)d_ws;
  size_t off = 0;
  float* xps = (float*)(ws + off); off += (size_t)Bsz * Tsz * Hsz * 4;  // 128 MiB
  float* U   = (float*)(ws + off); off += (size_t)Bsz * Tsz * KH * 4;   //  64 MiB
  unsigned* Q0 = (unsigned*)(ws + off); off += (size_t)32 * Hsz * 4 * 4;// 256 KiB
  unsigned* Q1 = (unsigned*)(ws + off); off += (size_t)32 * KH  * 4 * 4;// 128 KiB
  unsigned* Q2 = (unsigned*)(ws + off); off += (size_t)16 * Hsz * 4 * 4;// 128 KiB
  float* CS0   = (float*)(ws + off); off += 512 * 4;
  float* CS1   = (float*)(ws + off); off += 256 * 4;
  float* CS2   = (float*)(ws + off); off += 512 * 4;
  float* Wc    = (float*)(ws + off); off += (size_t)Isz * KH * 4;       // 128 KiB
  float* bU    = (float*)(ws + off); off += 256 * 4;

  const float* W1a = W_tau1;                     // rows 0..511
  const float* W1b = W_tau1 + (size_t)Hsz * KH;  // rows 512..1023

  const int M = Bsz * Tsz;  // 65536

  // opt-in to 144 KB dynamic LDS for the scan kernel
  (void)hipFuncSetAttribute((const void*)scan_kernel,
                            hipFuncAttributeMaxDynamicSharedMemorySize, 147456);

  // weight quantization + fused-U weight precompute (all small, independent)
  drive_scale_kernel<<<2, 256, 0, stream>>>(W_rec, CS0);
  drive_quant_kernel<<<256, 256, 0, stream>>>(W_rec, CS0, Q0);
  tau1_scale_kernel<<<1, 256, 0, stream>>>(W1b, CS1);
  tau1_quant_kernel<<<128, 256, 0, stream>>>(W1b, CS1, Q1);
  tau2_scale_kernel<<<2, 256, 0, stream>>>(W_tau2, CS2);
  tau2_quant_kernel<<<128, 256, 0, stream>>>(W_tau2, CS2, Q2);
  wc_kernel<<<Isz, 256, 0, stream>>>(W_in, W1a, Wc);
  bu_kernel<<<1, 256, 0, stream>>>(b_in, W1a, b_tau1, bU);

  // xp = x @ W_in + b_in            [65536,128]@[128,512]
  {
    dim3 grid(M / 64, Hsz / 128);
    gemm_bias_kernel<<<grid, 256, 0, stream>>>(x, W_in, b_in, xps, M, Hsz, Isz);
  }
  // U = x @ Wc + bU                 [65536,128]@[128,256]  (== xp@W1a + b_tau1)
  {
    dim3 grid(M / 64, KH / 128);
    gemm_bias_kernel<<<grid, 256, 0, stream>>>(x, Wc, bU, U, M, KH, Isz);
  }
  // scan (64 WGs, one per batch element; 144 KB dynamic LDS)
  scan_kernel<<<Bsz, 512, 147456, stream>>>(xps, U, Q0, Q1, Q2,
                                            CS0, CS1, CS2, bias, b_tau2);
  // output projection
  outproj_kernel<<<M / 16, 256, 0, stream>>>(xps, W_out, b_out, out);
}

// Round 3
// 2846.579 us; speedup vs baseline: 1.2994x; 1.0177x over previous
//
#include <hip/hip_runtime.h>
#include <hip/hip_fp16.h>
#include <math.h>

#define Bsz 64
#define Tsz 1024
#define Isz 128
#define Hsz 512
#define KH  256   // H/2
#define Osz 10

// ---------------------------------------------------------------------------
// Register-tiled fp32 GEMM: C[M,N] = A[M,K] @ Bw[K,N] + bias[N]
// 64x128 block tile, 8x4 micro-tile, 256 threads.
// ---------------------------------------------------------------------------
__global__ __launch_bounds__(256) void gemm_bias_kernel(
    const float* __restrict__ A, const float* __restrict__ Bw,
    const float* __restrict__ bias, float* __restrict__ C,
    int M, int N, int K)
{
  __shared__ float As[32][68];   // [k][m], padded
  const int tid = threadIdx.x;
  const int m0 = blockIdx.x * 64;
  const int n0 = blockIdx.y * 128;
  const int ty = tid >> 5, tx = tid & 31;

  float acc[8][4] = {{0.f}};

  for (int kk = 0; kk < K; kk += 32) {
    __syncthreads();
#pragma unroll
    for (int i = tid; i < 64 * 32; i += 256) {
      int m = i >> 5, k = i & 31;
      As[k][m] = A[(size_t)(m0 + m) * K + kk + k];
    }
    __syncthreads();
#pragma unroll
    for (int k = 0; k < 32; ++k) {
      const float4 bv = *(const float4*)(&Bw[(size_t)(kk + k) * N + n0 + tx * 4]);
      float a[8];
#pragma unroll
      for (int i = 0; i < 8; ++i) a[i] = As[k][ty * 8 + i];
#pragma unroll
      for (int i = 0; i < 8; ++i) {
        acc[i][0] = fmaf(a[i], bv.x, acc[i][0]);
        acc[i][1] = fmaf(a[i], bv.y, acc[i][1]);
        acc[i][2] = fmaf(a[i], bv.z, acc[i][2]);
        acc[i][3] = fmaf(a[i], bv.w, acc[i][3]);
      }
    }
  }

  const float4 bb = *(const float4*)(&bias[n0 + tx * 4]);
#pragma unroll
  for (int i = 0; i < 8; ++i) {
    float4 v;
    v.x = acc[i][0] + bb.x; v.y = acc[i][1] + bb.y;
    v.z = acc[i][2] + bb.z; v.w = acc[i][3] + bb.w;
    *(float4*)(&C[(size_t)(m0 + ty * 8 + i) * N + n0 + tx * 4]) = v;
  }
}

// ---------------------------------------------------------------------------
// Wc = W_in @ W1a  (128x512 @ 512x256 -> 128x256), one block per row i.
// ---------------------------------------------------------------------------
__global__ __launch_bounds__(256) void wc_kernel(
    const float* __restrict__ W_in, const float* __restrict__ W1a,
    float* __restrict__ Wc)
{
  __shared__ float row[Hsz];
  const int i = blockIdx.x, c = threadIdx.x;
  for (int h = c; h < Hsz; h += 256) row[h] = W_in[(size_t)i * Hsz + h];
  __syncthreads();
  float acc = 0.f;
#pragma unroll 8
  for (int h = 0; h < Hsz; ++h)
    acc = fmaf(row[h], W1a[(size_t)h * KH + c], acc);
  Wc[(size_t)i * KH + c] = acc;
}

// b_U = b_in @ W1a + b_tau1  (256)
__global__ __launch_bounds__(256) void bu_kernel(
    const float* __restrict__ b_in, const float* __restrict__ W1a,
    const float* __restrict__ b_tau1, float* __restrict__ bU)
{
  const int c = threadIdx.x;
  float acc = b_tau1[c];
#pragma unroll 8
  for (int h = 0; h < Hsz; ++h)
    acc = fmaf(b_in[h], W1a[(size_t)h * KH + c], acc);
  bU[c] = acc;
}

// ---------------------------------------------------------------------------
// i8 dot4
// ---------------------------------------------------------------------------
__device__ __forceinline__ int dot4i8(int a, int b, int acc) {
#if __has_builtin(__builtin_amdgcn_sdot4)
  return __builtin_amdgcn_sdot4(a, b, acc, false);
#else
  acc += ((a << 24) >> 24) * ((b << 24) >> 24);
  acc += ((a << 16) >> 24) * ((b << 16) >> 24);
  acc += ((a << 8)  >> 24) * ((b << 8)  >> 24);
  acc += (a >> 24) * (b >> 24);
  return acc;
#endif
}

// ---------------------------------------------------------------------------
// Quantizer layouts: [G groups x C cols] i8; group g, dword di, byte e covers
// source k = 16g + 4di + e; flat dword index = g*(C*4)+c*4+di.
// ---------------------------------------------------------------------------

// drive: col j = output row of W_rec (512 cols, 32 groups over k=512)
__global__ __launch_bounds__(256) void drive_scale_kernel(
    const float* __restrict__ W_rec, float* __restrict__ CS0)
{
  const int j = blockIdx.x * 256 + threadIdx.x;  // 512
  float m = 0.f;
  for (int k = 0; k < Hsz; ++k)
    m = fmaxf(m, fabsf(W_rec[(size_t)j * Hsz + k]));
  CS0[j] = m;
}

__global__ __launch_bounds__(256) void drive_quant_kernel(
    const float* __restrict__ W_rec, const float* __restrict__ CS0,
    unsigned* __restrict__ Q0)
{
  int i = blockIdx.x * 256 + threadIdx.x;  // 65536 dwords
  if (i >= 32 * Hsz * 4) return;
  int di = i & 3, j = (i >> 2) & 511, g = i >> 11;
  int k0 = 16 * g + 4 * di;
  float ma = CS0[j];
  float r = (ma > 0.f) ? (127.f / ma) : 0.f;
  unsigned out = 0;
#pragma unroll
  for (int e = 0; e < 4; ++e) {
    int q = __float2int_rn(W_rec[(size_t)j * Hsz + k0 + e] * r);
    out |= ((unsigned)(q & 255)) << (8 * e);
  }
  Q0[i] = out;
}

// tau1: col c (256 cols), 32 groups over j=512 (source W1b[j][c])
__global__ __launch_bounds__(256) void tau1_scale_kernel(
    const float* __restrict__ W1b, float* __restrict__ CS1)
{
  const int c = threadIdx.x;  // 256
  float m = 0.f;
  for (int j = 0; j < Hsz; ++j)
    m = fmaxf(m, fabsf(W1b[(size_t)j * KH + c]));
  CS1[c] = m;
}

__global__ __launch_bounds__(256) void tau1_quant_kernel(
    const float* __restrict__ W1b, const float* __restrict__ CS1,
    unsigned* __restrict__ Q1)
{
  int i = blockIdx.x * 256 + threadIdx.x;  // 32768 dwords
  if (i >= 32 * KH * 4) return;
  int di = i & 3, c = (i >> 2) & 255, g = i >> 10;
  int j0 = 16 * g + 4 * di;
  float ma = CS1[c];
  float r = (ma > 0.f) ? (127.f / ma) : 0.f;
  unsigned out = 0;
#pragma unroll
  for (int e = 0; e < 4; ++e) {
    int q = __float2int_rn(W1b[(size_t)(j0 + e) * KH + c] * r);
    out |= ((unsigned)(q & 255)) << (8 * e);
  }
  Q1[i] = out;
}

// tau2: col j (512 cols), 16 groups over k=256 (source W_tau2[k][j])
__global__ __launch_bounds__(256) void tau2_scale_kernel(
    const float* __restrict__ W_tau2, float* __restrict__ CS2)
{
  const int j = blockIdx.x * 256 + threadIdx.x;  // 512
  float m = 0.f;
  for (int k = 0; k < KH; ++k)
    m = fmaxf(m, fabsf(W_tau2[(size_t)k * Hsz + j]));
  CS2[j] = m;
}

__global__ __launch_bounds__(256) void tau2_quant_kernel(
    const float* __restrict__ W_tau2, const float* __restrict__ CS2,
    unsigned* __restrict__ Q2)
{
  int i = blockIdx.x * 256 + threadIdx.x;  // 32768 dwords
  if (i >= 16 * Hsz * 4) return;
  int di = i & 3, j = (i >> 2) & 511, g = i >> 11;
  int k0 = 16 * g + 4 * di;
  float ma = CS2[j];
  float r = (ma > 0.f) ? (127.f / ma) : 0.f;
  unsigned out = 0;
#pragma unroll
  for (int e = 0; e < 4; ++e) {
    int q = __float2int_rn(W_tau2[(size_t)(k0 + e) * Hsz + j] * r);
    out |= ((unsigned)(q & 255)) << (8 * e);
  }
  Q2[i] = out;
}

// keep a loaded uint4 pinned in VGPRs: the loop consumes the asm RESULT,
// which the compiler cannot rematerialize or sink back into the loop.
#define KEEP4(v) asm volatile("" : "+v"((v).x), "+v"((v).y), "+v"((v).z), "+v"((v).w))

// ---------------------------------------------------------------------------
// Sequential scan. One WG (512 threads) per batch element. All matvecs i8.
//
// R15 change: R14's __launch_bounds__(512,2) did NOT unlock the 256-VGPR
// tier (VGPR_Count stayed 128): the backend can't see the 144 KB *dynamic*
// LDS, so its occupancy heuristic still targeted 4 waves/EU and legally
// re-sank the loop-invariant weight loads into the t-loop (L2-latency bound,
// VALUBusy 14%). Force it with BOTH levers:
//   - amdgpu_waves_per_eu(2,2): pin occupancy to 2 waves/EU (== the 1 WG/CU
//     the LDS forces anyway) -> 256-VGPR budget is the explicit target.
//   - KEEP4 asm on every preloaded weight: the t-loop uses asm results,
//     which cannot be remat'd/sunk -> weights stay register-resident.
// Persistent: drive g0..25 (104 VGPR) + tau1 g0..15 (64 VGPR) = 168.
// Drive g26..29 streamed from L2 each step (32 KiB, hidden under P1/P2);
// g30,31 + all tau2 in LDS (144 KB).
// ---------------------------------------------------------------------------
__global__ __attribute__((amdgpu_flat_work_group_size(512, 512),
                          amdgpu_waves_per_eu(2, 2)))
void scan_kernel(
    float* __restrict__ xps,           // in: xp [B,T,H]; out: hs [B,T,H]
    const float* __restrict__ U,       // [B,T,KH] (b_tau1 already added)
    const unsigned* __restrict__ Q0,   // i8 drive [32][512][4]
    const unsigned* __restrict__ Q1,   // i8 tau1  [32][256][4]
    const unsigned* __restrict__ Q2,   // i8 tau2  [16][512][4]
    const float* __restrict__ CS0,     // [512]
    const float* __restrict__ CS1,     // [256]
    const float* __restrict__ CS2,     // [512]
    const float* __restrict__ bias,    // [H]
    const float* __restrict__ b_tau2)  // [H]
{
  const int b = blockIdx.x;
  const int tid = threadIdx.x;
  const int hs = tid >> 8;             // tau1 k-half
  const int c  = tid & 255;            // tau1 column

  extern __shared__ __align__(16) uint4 Wlds[];
  __shared__ __align__(16) int Hq[2][128];       // i8 h, double-buffered
  __shared__ __align__(16) unsigned char Aq[KH]; // i8 A (256 B)
  __shared__ float scaleA[4];                    // per-wave A amax
  __shared__ int parti[2][KH];

  const float bias_r = bias[tid];
  const float bt2_r  = b_tau2[tid];
  const float cs0r = CS0[tid] * (1.0f / 16129.0f);  // /127^2
  const float csr  = CS1[c]   * (1.0f / 16129.0f);
  const float cs2r = CS2[tid] * (1.0f / 16129.0f);
  float hold = 0.f;
  if (tid < 128) { Hq[0][tid] = 0; Hq[1][tid] = 0; }

  float* xprow = xps + (size_t)b * Tsz * Hsz;
  const float* Urow = U + (size_t)b * Tsz * KH;

  const uint4* __restrict__ q0 = (const uint4*)Q0 + tid;                 // stride 512
  const uint4* __restrict__ q1 = (const uint4*)Q1 + (size_t)(hs * 16) * 256 + c; // stride 256
  const uint4* __restrict__ q2 = (const uint4*)Q2 + tid;                 // stride 512
  const uint4* Aq4 = (const uint4*)Aq;

  // --- one-time LDS staging: 16 tau2 groups + drive groups 30,31 ---
#pragma unroll
  for (int i = 0; i < 16; ++i)
    Wlds[i * 512 + tid] = q2[(size_t)i * 512];
#pragma unroll
  for (int i = 0; i < 2; ++i)
    Wlds[8192 + i * 512 + tid] = q0[(size_t)(30 + i) * 512];

  // --- one-time REGISTER staging: drive g0..25 (104 VGPR), tau1 all (64) ---
  uint4 w0r[26];
#pragma unroll
  for (int g = 0; g < 26; ++g) w0r[g] = q0[(size_t)g * 512];
  uint4 w1r[16];
#pragma unroll
  for (int g = 0; g < 16; ++g) w1r[g] = q1[(size_t)g * 256];

  // pin them: loads above cannot be sunk past these, and the loop consumes
  // the pinned values.
#pragma unroll
  for (int g = 0; g < 26; ++g) KEEP4(w0r[g]);
#pragma unroll
  for (int g = 0; g < 16; ++g) KEEP4(w1r[g]);

  __syncthreads();

  // step-0 operands (subsequent steps prefetched inside the loop)
  float xpv = xprow[tid];
  float Uv  = (tid < KH) ? Urow[tid] : 0.f;

  for (int t = 0; t < Tsz; ++t) {
    const uint4* h4 = (const uint4*)Hq[t & 1];

    // streamed drive groups 26..29 -- issued first so L2 latency hides
    // under P1/P2
    const uint4 s26 = q0[(size_t)26 * 512];
    const uint4 s27 = q0[(size_t)27 * 512];
    const uint4 s28 = q0[(size_t)28 * 512];
    const uint4 s29 = q0[(size_t)29 * 512];

    // --- P1: tau1 partial (i8), 16 groups from registers ---
    int a0 = 0, a1 = 0;
#pragma unroll
    for (int g = 0; g < 16; ++g) {
      const uint4 w  = w1r[g];
      const uint4 hv = h4[hs * 16 + g];
      a0 = dot4i8((int)w.x, (int)hv.x, a0); a1 = dot4i8((int)w.y, (int)hv.y, a1);
      a0 = dot4i8((int)w.z, (int)hv.z, a0); a1 = dot4i8((int)w.w, (int)hv.w, a1);
    }
    parti[hs][c] = a0 + a1;
    __syncthreads();                                   // sync1

    // --- P2: A + per-wave (64-lane segment) quantization ---
    if (tid < KH) {
      float aval = fmaxf(Uv + (float)(parti[0][tid] + parti[1][tid]) * csr, 0.f);
      float m = aval;
#pragma unroll
      for (int off = 32; off >= 1; off >>= 1)
        m = fmaxf(m, __shfl_xor(m, off));
      if ((tid & 63) == 0) scaleA[tid >> 6] = m;
      const float r = (m > 0.f) ? (127.f / m) : 0.f;
      Aq[tid] = (unsigned char)__float2int_rn(aval * r);
    }
    __syncthreads();                                   // sync2

    // prefetch next-step xp/U (one row ahead; last step reads into the next
    // workspace region -- mapped memory, value discarded)
    const float xpn = xprow[Hsz + tid];
    const float Un  = (tid < KH) ? Urow[KH + tid] : 0.f;

    // --- P3: drive (26 reg + 4 streamed + 2 LDS groups) fused with tau2 ---
    int d0i = 0, d1i = 0;
    int t2a0 = 0, t2a1 = 0;
    float s = bt2_r;
#pragma unroll
    for (int g = 0; g < 16; ++g) {
      uint4 w0, w1;
      if (g < 13) {
        w0 = w0r[2 * g];
        w1 = w0r[2 * g + 1];
      } else if (g == 13) {
        w0 = s26; w1 = s27;
      } else if (g == 14) {
        w0 = s28; w1 = s29;
      } else {
        w0 = Wlds[8192 + tid];
        w1 = Wlds[8192 + 512 + tid];
      }
      const uint4 hv0 = h4[2 * g], hv1 = h4[2 * g + 1];
      d0i = dot4i8((int)w0.x, (int)hv0.x, d0i); d1i = dot4i8((int)w0.y, (int)hv0.y, d1i);
      d0i = dot4i8((int)w0.z, (int)hv0.z, d0i); d1i = dot4i8((int)w0.w, (int)hv0.w, d1i);
      d0i = dot4i8((int)w1.x, (int)hv1.x, d0i); d1i = dot4i8((int)w1.y, (int)hv1.y, d1i);
      d0i = dot4i8((int)w1.z, (int)hv1.z, d0i); d1i = dot4i8((int)w1.w, (int)hv1.w, d1i);

      const uint4 wt = Wlds[g * 512 + tid];
      const uint4 av = Aq4[g];
      t2a0 = dot4i8((int)wt.x, (int)av.x, t2a0); t2a1 = dot4i8((int)wt.y, (int)av.y, t2a1);
      t2a0 = dot4i8((int)wt.z, (int)av.z, t2a0); t2a1 = dot4i8((int)wt.w, (int)av.w, t2a1);
      if ((g & 3) == 3) {
        s += (float)(t2a0 + t2a1) * cs2r * scaleA[g >> 2];
        t2a0 = 0; t2a1 = 0;
      }
    }

    // --- epilogue: tau, tanh, Euler update ---
    const float d = xpv + bias_r + (float)(d0i + d1i) * cs0r;
    const float tau = 5.0f + 45.0f / (1.0f + __expf(-s));
    const float e2 = __expf(2.0f * d);
    const float drv = 1.0f - 2.0f / (e2 + 1.0f);       // tanh
    const float hnew = hold + (drv - hold) / tau;
    hold = hnew;
    ((char*)Hq[(t + 1) & 1])[tid] = (char)(__float2int_rn(hnew * 127.f) & 255);
    xprow[tid] = hnew;                                 // hs output (dead xp slot)
    __syncthreads();                                   // sync3

    xpv = xpn; Uv = Un;
    xprow += Hsz;
    Urow  += KH;
  }
}

// ---------------------------------------------------------------------------
// Epilogue: out[m,o] = hs[m,:] @ W_out[:,o] + b_out[o].
// 16 rows/block staged to LDS via coalesced float4 (+4 pad to spread banks);
// W_out also in LDS. Inner loop = b128 LDS h-reads + scalar LDS W + FMA.
// ---------------------------------------------------------------------------
__global__ __launch_bounds__(256) void outproj_kernel(
    const float* __restrict__ hs, const float* __restrict__ W_out,
    const float* __restrict__ b_out, float* __restrict__ out)
{
  __shared__ float hsL[16][516];       // 516 = 512+4: rows spread across banks
  __shared__ float WL[Hsz * Osz];      // 20 KB
  const int tid = threadIdx.x;
  const size_t m0 = (size_t)blockIdx.x * 16;

  for (int i = tid; i < Hsz * Osz; i += 256) WL[i] = W_out[i];

  const float4* src = (const float4*)(hs + m0 * Hsz);  // 2048 float4, contiguous
#pragma unroll
  for (int i = 0; i < 8; ++i) {
    int idx = i * 256 + tid;
    *(float4*)&hsL[idx >> 7][(idx & 127) * 4] = src[idx];
  }
  __syncthreads();

  const int r = tid >> 4, o = tid & 15;
  if (o < Osz) {
    float acc = b_out[o];
#pragma unroll 8
    for (int k4 = 0; k4 < 128; ++k4) {
      const float4 h4 = *(const float4*)&hsL[r][k4 * 4];
      acc = fmaf(h4.x, WL[(4 * k4 + 0) * Osz + o], acc);
      acc = fmaf(h4.y, WL[(4 * k4 + 1) * Osz + o], acc);
      acc = fmaf(h4.z, WL[(4 * k4 + 2) * Osz + o], acc);
      acc = fmaf(h4.w, WL[(4 * k4 + 3) * Osz + o], acc);
    }
    out[(m0 + r) * Osz + o] = acc;
  }
}

// ---------------------------------------------------------------------------
extern "C" void kernel_launch(void* const* d_in, const int* in_sizes, int n_in,
                              void* d_out, int out_size, void* d_ws, size_t ws_size,
                              hipStream_t stream) {
  (void)in_sizes; (void)n_in; (void)out_size; (void)ws_size;

  const float* x      = (const float*)d_in[0];
  const float* W_in   = (const float*)d_in[1];
  const float* b_in   = (const float*)d_in[2];
  const float* W_rec  = (const float*)d_in[3];
  const float* bias   = (const float*)d_in[4];
  const float* W_tau1 = (const float*)d_in[5];
  const float* b_tau1 = (const float*)d_in[6];
  const float* W_tau2 = (const float*)d_in[7];
  const float* b_tau2 = (const float*)d_in[8];
  const float* W_out  = (const float*)d_in[9];
  const float* b_out  = (const float*)d_in[10];
  float* out = (float*)d_out;

  char* ws = (char*)d_ws;
  size_t off = 0;
  float* xps = (float*)(ws + off); off += (size_t)Bsz * Tsz * Hsz * 4;  // 128 MiB
  float* U   = (float*)(ws + off); off += (size_t)Bsz * Tsz * KH * 4;   //  64 MiB
  unsigned* Q0 = (unsigned*)(ws + off); off += (size_t)32 * Hsz * 4 * 4;// 256 KiB
  unsigned* Q1 = (unsigned*)(ws + off); off += (size_t)32 * KH  * 4 * 4;// 128 KiB
  unsigned* Q2 = (unsigned*)(ws + off); off += (size_t)16 * Hsz * 4 * 4;// 128 KiB
  float* CS0   = (float*)(ws + off); off += 512 * 4;
  float* CS1   = (float*)(ws + off); off += 256 * 4;
  float* CS2   = (float*)(ws + off); off += 512 * 4;
  float* Wc    = (float*)(ws + off); off += (size_t)Isz * KH * 4;       // 128 KiB
  float* bU    = (float*)(ws + off); off += 256 * 4;

  const float* W1a = W_tau1;                     // rows 0..511
  const float* W1b = W_tau1 + (size_t)Hsz * KH;  // rows 512..1023

  const int M = Bsz * Tsz;  // 65536

  // opt-in to 144 KB dynamic LDS for the scan kernel
  (void)hipFuncSetAttribute((const void*)scan_kernel,
                            hipFuncAttributeMaxDynamicSharedMemorySize, 147456);

  // weight quantization + fused-U weight precompute (all small, independent)
  drive_scale_kernel<<<2, 256, 0, stream>>>(W_rec, CS0);
  drive_quant_kernel<<<256, 256, 0, stream>>>(W_rec, CS0, Q0);
  tau1_scale_kernel<<<1, 256, 0, stream>>>(W1b, CS1);
  tau1_quant_kernel<<<128, 256, 0, stream>>>(W1b, CS1, Q1);
  tau2_scale_kernel<<<2, 256, 0, stream>>>(W_tau2, CS2);
  tau2_quant_kernel<<<128, 256, 0, stream>>>(W_tau2, CS2, Q2);
  wc_kernel<<<Isz, 256, 0, stream>>>(W_in, W1a, Wc);
  bu_kernel<<<1, 256, 0, stream>>>(b_in, W1a, b_tau1, bU);

  // xp = x @ W_in + b_in            [65536,128]@[128,512]
  {
    dim3 grid(M / 64, Hsz / 128);
    gemm_bias_kernel<<<grid, 256, 0, stream>>>(x, W_in, b_in, xps, M, Hsz, Isz);
  }
  // U = x @ Wc + bU                 [65536,128]@[128,256]  (== xp@W1a + b_tau1)
  {
    dim3 grid(M / 64, KH / 128);
    gemm_bias_kernel<<<grid, 256, 0, stream>>>(x, Wc, bU, U, M, KH, Isz);
  }
  // scan (64 WGs, one per batch element; 144 KB dynamic LDS)
  scan_kernel<<<Bsz, 512, 147456, stream>>>(xps, U, Q0, Q1, Q2,
                                            CS0, CS1, CS2, bias, b_tau2);
  // output projection
  outproj_kernel<<<M / 16, 256, 0, stream>>>(xps, W_out, b_out, out);
}